// Round 3
// baseline (668.131 us; speedup 1.0000x reference)
//
#include <hip/hip_runtime.h>
#include <hip/hip_cooperative_groups.h>
namespace cg = cooperative_groups;

#define TPB 512
#define GRID 256
#define NORM11 0x1p-11f   // 1/sqrt(2^22), exact
#define BST 36            // pass-B LDS row stride (mult of 4 -> float4 LDS ok)

// XOR swizzle for pass-A LDS region: bits 5-7 -> bank bits 2-4. Involution,
// float4-safe (only flips bits 2-4).
__device__ __forceinline__ int swz(int f) { return f ^ (((f >> 5) & 7) << 2); }

// radix-4 butterfly = two FWHT stages on (a,b,c,d) spaced h, 2h
__device__ __forceinline__ void bf4(float& a, float& b, float& c, float& d) {
  const float ab = a + b, amb = a - b, cd = c + d, cmd = c - d;
  a = ab + cd; b = amb + cmd; c = ab - cd; d = amb - cmd;
}

// ---------------- pass-A span: FWHT over low 13 bits of one 8192-float span ---------
// V=0: pre = B[g] * sum_t w[t]*tv[t][g]
// V=1: pre = src[Pi[g]]          (G==1 skipped)
// V=2: plain load; post *2^-11   (in-place ok)
// V=3: pre = src[invPi[g]]
template<int V>
__device__ __forceinline__ void spanA(
    const float* __restrict__ src, float* __restrict__ dst,
    const float* __restrict__ aux, const int* __restrict__ idx,
    const float* __restrict__ w8, long D, int sp, float* lds, int t)
{
  const long base = (long)sp * 8192;
  float r[16];
  #pragma unroll
  for (int k = 0; k < 4; k++) {
    const long g = base + 2048*k + 4*t;
    float4 v;
    if constexpr (V == 0) {
      float ax = 0.f, ay = 0.f, az = 0.f, aw = 0.f;
      #pragma unroll
      for (int tt = 0; tt < 8; tt++) {
        const float4 x = *(const float4*)(src + (long)tt*D + g);
        const float wv = w8[tt];
        ax = fmaf(wv, x.x, ax); ay = fmaf(wv, x.y, ay);
        az = fmaf(wv, x.z, az); aw = fmaf(wv, x.w, aw);
      }
      const float4 b4 = *(const float4*)(aux + g);
      v.x = ax*b4.x; v.y = ay*b4.y; v.z = az*b4.z; v.w = aw*b4.w;
    } else if constexpr (V == 1 || V == 3) {
      const int4 p4 = *(const int4*)(idx + g);
      v.x = src[p4.x]; v.y = src[p4.y]; v.z = src[p4.z]; v.w = src[p4.w];
    } else {
      v = *(const float4*)(src + g);
    }
    r[4*k+0] = v.x; r[4*k+1] = v.y; r[4*k+2] = v.z; r[4*k+3] = v.w;
  }

  // register stages: h=1,2 (within float4) and h=2048,4096 (across k)
  #pragma unroll
  for (int k = 0; k < 4; k++) bf4(r[4*k+0], r[4*k+1], r[4*k+2], r[4*k+3]);
  #pragma unroll
  for (int j = 0; j < 4; j++) bf4(r[j], r[4+j], r[8+j], r[12+j]);

  #pragma unroll
  for (int k = 0; k < 4; k++) {
    float4 v; v.x=r[4*k+0]; v.y=r[4*k+1]; v.z=r[4*k+2]; v.w=r[4*k+3];
    *(float4*)(lds + swz(2048*k + 4*t)) = v;
  }
  __syncthreads();

  // LDS stages h=4..1024: 4 radix-4 pairs + 1 single
  #pragma unroll
  for (int sp2 = 0; sp2 < 4; sp2++) {
    const int s = 2 + 2*sp2, h = 1 << s;
    #pragma unroll
    for (int k = 0; k < 4; k++) {
      const int q = t + TPB*k;
      const int i = ((q >> s) << (s+2)) | (q & (h-1));
      const int f0 = swz(i), f1 = swz(i+h), f2 = swz(i+2*h), f3 = swz(i+3*h);
      float a = lds[f0], b = lds[f1], c = lds[f2], d = lds[f3];
      bf4(a, b, c, d);
      lds[f0] = a; lds[f1] = b; lds[f2] = c; lds[f3] = d;
    }
    __syncthreads();
  }
  #pragma unroll
  for (int k = 0; k < 8; k++) {
    const int q = t + TPB*k;
    const int i = ((q >> 10) << 11) | (q & 1023);
    const int f0 = swz(i), f1 = swz(i + 1024);
    const float u = lds[f0], w = lds[f1];
    lds[f0] = u + w; lds[f1] = u - w;
  }
  __syncthreads();

  #pragma unroll
  for (int k = 0; k < 4; k++) {
    const long g = base + 2048*k + 4*t;
    float4 v = *(const float4*)(lds + swz(2048*k + 4*t));
    if constexpr (V == 2) { v.x*=NORM11; v.y*=NORM11; v.z*=NORM11; v.w*=NORM11; }
    *(float4*)(dst + g) = v;
  }
  __syncthreads();   // lds reused by caller's next span
}

// ---------------- pass-B tile: FWHT over high 9 bits; 512 rows x 32 cols ------------
__device__ __forceinline__ void fwht_hi(float* lds, int t)
{
  #pragma unroll
  for (int sp = 0; sp < 4; sp++) {
    const int s = 2*sp, h = 1 << s;
    #pragma unroll
    for (int k = 0; k < 8; k++) {
      const int q = t + TPB*k;                 // 4096 quads
      const int col = q & 31, qr = q >> 5;     // 128 row-quads
      const int i = ((qr >> s) << (s+2)) | (qr & (h-1));
      const int f0 = i*BST+col, f1 = (i+h)*BST+col;
      const int f2 = (i+2*h)*BST+col, f3 = (i+3*h)*BST+col;
      float a = lds[f0], b = lds[f1], c = lds[f2], d = lds[f3];
      bf4(a, b, c, d);
      lds[f0] = a; lds[f1] = b; lds[f2] = c; lds[f3] = d;
    }
    __syncthreads();
  }
  #pragma unroll
  for (int k = 0; k < 16; k++) {               // single stage h=256
    const int q = t + TPB*k;                   // 8192 butterflies
    const int col = q & 31, i = q >> 5;
    const int f0 = i*BST+col, f1 = f0 + 256*BST;
    const float u = lds[f0], w = lds[f1];
    lds[f0] = u + w; lds[f1] = u - w;
  }
  __syncthreads();
}

// V=0: post *2^-11 (in-place) | V=1: hi, *2^-11*mask, hi (in-place) |
// V=2: post out = v*2^-11*B + pretrained
template<int V>
__device__ __forceinline__ void tileB(
    const float* __restrict__ src, float* __restrict__ dst,
    const unsigned char* __restrict__ mask,
    const float* __restrict__ bvec, const float* __restrict__ pvec,
    int tb, float* lds, int t)
{
  const long J0 = (long)tb * 32;
  #pragma unroll
  for (int k = 0; k < 8; k++) {
    const int e4 = t + TPB*k;                  // 4096 float4
    const int row = e4 >> 3, c = (e4 & 7)*4;   // full 128B line per row-octet
    const float4 v = *(const float4*)(src + (long)row*8192 + J0 + c);
    *(float4*)(lds + row*BST + c) = v;
  }
  __syncthreads();

  fwht_hi(lds, t);

  if constexpr (V == 1) {
    #pragma unroll
    for (int k = 0; k < 8; k++) {
      const int e4 = t + TPB*k;
      const int row = e4 >> 3, c = (e4 & 7)*4;
      const long g = (long)row*8192 + J0 + c;
      const uchar4 m4 = *(const uchar4*)(mask + g);
      const int ba = row*BST + c;
      lds[ba+0] *= NORM11 * (float)m4.x;
      lds[ba+1] *= NORM11 * (float)m4.y;
      lds[ba+2] *= NORM11 * (float)m4.z;
      lds[ba+3] *= NORM11 * (float)m4.w;
    }
    __syncthreads();
    fwht_hi(lds, t);
  }

  #pragma unroll
  for (int k = 0; k < 8; k++) {
    const int e4 = t + TPB*k;
    const int row = e4 >> 3, c = (e4 & 7)*4;
    const long g = (long)row*8192 + J0 + c;
    float4 v = *(const float4*)(lds + row*BST + c);
    if constexpr (V == 0) { v.x*=NORM11; v.y*=NORM11; v.z*=NORM11; v.w*=NORM11; }
    if constexpr (V == 2) {
      const float4 b4 = *(const float4*)(bvec + g);
      const float4 p4 = *(const float4*)(pvec + g);
      v.x = fmaf(v.x*NORM11, b4.x, p4.x); v.y = fmaf(v.y*NORM11, b4.y, p4.y);
      v.z = fmaf(v.z*NORM11, b4.z, p4.z); v.w = fmaf(v.w*NORM11, b4.w, p4.w);
    }
    *(float4*)(dst + g) = v;
  }
  __syncthreads();
}

// ---------------- the whole chain as one cooperative kernel -------------------------
__global__ __launch_bounds__(TPB, 1) void fastfood_all(
    const float* __restrict__ tv, const float* __restrict__ w8,
    const float* __restrict__ prew, const float* __restrict__ Bv,
    const int* __restrict__ Pi, const int* __restrict__ invPi,
    const int* __restrict__ rowIx, int m,
    float* bufA, unsigned char* mask, float* out, long D)
{
  __shared__ float lds[512*BST];               // 73728 B
  const int t = threadIdx.x, b = blockIdx.x;
  cg::grid_group grid = cg::this_grid();

  // P1: combine 8 tasks, *B, FWHT1-low  (tv -> bufA)
  spanA<0>(tv, bufA, Bv, nullptr, w8, D, 2*b,   lds, t);
  spanA<0>(tv, bufA, Bv, nullptr, w8, D, 2*b+1, lds, t);
  grid.sync();

  // P2: FWHT1-high, *2^-11 (bufA in-place) + mask memset slice (tv now dead)
  tileB<0>(bufA, bufA, nullptr, nullptr, nullptr, b, lds, t);
  {
    unsigned int* m32 = (unsigned int*)mask;   // D/4 uints total, 4096 per block
    const int base = b*4096;
    #pragma unroll
    for (int k = 0; k < 8; k++) m32[base + t + TPB*k] = 0u;
  }
  grid.sync();

  // P3: gather Pi, FWHT2-low (bufA -> out) + mask scatter slice
  spanA<1>(bufA, out, nullptr, Pi, nullptr, D, 2*b,   lds, t);
  spanA<1>(bufA, out, nullptr, Pi, nullptr, D, 2*b+1, lds, t);
  {
    const int chunk = (m + GRID - 1)/GRID;
    const int lo = b*chunk, hi = (lo + chunk < m) ? lo + chunk : m;
    for (int j = lo + t; j < hi; j += TPB) mask[rowIx[j]] = 1;
  }
  grid.sync();

  // P4: FWHT2-high, *2^-11, *mask, FWHT3-high (out in-place)
  tileB<1>(out, out, mask, nullptr, nullptr, b, lds, t);
  grid.sync();

  // P5: FWHT3-low, *2^-11 (out in-place)
  spanA<2>(out, out, nullptr, nullptr, nullptr, D, 2*b,   lds, t);
  spanA<2>(out, out, nullptr, nullptr, nullptr, D, 2*b+1, lds, t);
  grid.sync();

  // P6: gather invPi, FWHT4-low (out -> bufA)
  spanA<3>(out, bufA, nullptr, invPi, nullptr, D, 2*b,   lds, t);
  spanA<3>(out, bufA, nullptr, invPi, nullptr, D, 2*b+1, lds, t);
  grid.sync();

  // P7: FWHT4-high, *2^-11*B + pretrained (bufA -> out)
  tileB<2>(bufA, out, nullptr, Bv, prew, b, lds, t);
}

extern "C" void kernel_launch(void* const* d_in, const int* in_sizes, int n_in,
                              void* d_out, int out_size, void* d_ws, size_t ws_size,
                              hipStream_t stream)
{
  (void)n_in; (void)out_size;
  const float* tv    = (const float*)d_in[0];  // (T, D)
  const float* w     = (const float*)d_in[1];  // (T,)
  const float* prew  = (const float*)d_in[2];  // (D,)
  const float* Bv    = (const float*)d_in[3];
  // d_in[4] = G == ones, unused
  const int*   Pi    = (const int*)d_in[5];
  const int*   invPi = (const int*)d_in[6];
  const int*   rowIx = (const int*)d_in[7];
  long D = (long)in_sizes[2];                  // 2^22
  int  m = in_sizes[7];
  float* out = (float*)d_out;

  float* bufA; unsigned char* mask;
  const size_t need = (size_t)D*sizeof(float) + (size_t)D;
  if (ws_size >= need) {
    bufA = (float*)d_ws;
    mask = (unsigned char*)d_ws + (size_t)D*sizeof(float);
  } else {
    bufA = (float*)d_in[0];                    // tv fully consumed in P1
    mask = (unsigned char*)((float*)d_in[0] + D);
  }

  void* args[] = {
    (void*)&tv, (void*)&w, (void*)&prew, (void*)&Bv, (void*)&Pi,
    (void*)&invPi, (void*)&rowIx, (void*)&m, (void*)&bufA,
    (void*)&mask, (void*)&out, (void*)&D
  };
  hipLaunchCooperativeKernel((const void*)fastfood_all, dim3(GRID), dim3(TPB),
                             args, 0, stream);
}

// Round 4
// 454.832 us; speedup vs baseline: 1.4690x; 1.4690x over previous
//
#include <hip/hip_runtime.h>

#define NORM11 0x1p-11f   // 1/sqrt(2^22), exact

// XOR swizzle for pass-A LDS: bits 5-7 -> bank bits 2-4. Involution, float4-safe.
__device__ __forceinline__ int swz(int f) { return f ^ (((f >> 5) & 7) << 2); }

// radix-4 butterfly = two FWHT stages on (a,b,c,d) spaced h, 2h
__device__ __forceinline__ void bf4(float& a, float& b, float& c, float& d) {
  const float ab = a + b, amb = a - b, cd = c + d, cmd = c - d;
  a = ab + cd; b = amb + cmd; c = ab - cd; d = amb - cmd;
}

// ---------------- pass A: FWHT over low 13 bits (one 8192-float span / block) -------
// Stage plan: h=1,2 (float4 lanes j) + h=2048,4096 (k) in regs;
// h=4..128 via shfl_xor (lane bits, no barriers);
// h=256,512,1024 via one LDS radix-8 round trip (1 barrier);
// stores: coalesced 256B/wave scalar stores straight from radix-8 regs.
// V=0: pre = B[g]*sum_t w[t]*tv[t][g]   (K1)
// V=1: pre = src[Pi[g]]                 (K3)
// V=2: plain load; post *2^-11          (K5, in-place ok)
// V=3: pre = src[invPi[g]]              (K6)
template<int V>
__global__ __launch_bounds__(512, 4) void passA(
    const float* __restrict__ src, float* __restrict__ dst,
    const float* __restrict__ aux, const int* __restrict__ idx,
    const float* __restrict__ w8, long D)
{
  __shared__ float lds[8192];
  const int t = threadIdx.x;
  const int lane = t & 63;
  const long base = (long)blockIdx.x * 8192;

  float wr[8];
  if constexpr (V == 0) {
    #pragma unroll
    for (int i = 0; i < 8; i++) wr[i] = w8[i];
  }

  // ---- load 4 coalesced float4 (e = 2048k + 4t + j) with fused pre-op ----
  float v[16];
  #pragma unroll
  for (int k = 0; k < 4; k++) {
    const long g = base + 2048*k + 4*t;
    float4 x;
    if constexpr (V == 0) {
      float ax = 0.f, ay = 0.f, az = 0.f, aw = 0.f;
      #pragma unroll
      for (int tt = 0; tt < 8; tt++) {
        const float4 q = *(const float4*)(src + (long)tt*D + g);
        ax = fmaf(wr[tt], q.x, ax); ay = fmaf(wr[tt], q.y, ay);
        az = fmaf(wr[tt], q.z, az); aw = fmaf(wr[tt], q.w, aw);
      }
      const float4 b4 = *(const float4*)(aux + g);
      x.x = ax*b4.x; x.y = ay*b4.y; x.z = az*b4.z; x.w = aw*b4.w;
    } else if constexpr (V == 1 || V == 3) {
      const int4 p4 = *(const int4*)(idx + g);
      x.x = src[p4.x]; x.y = src[p4.y]; x.z = src[p4.z]; x.w = src[p4.w];
    } else {
      x = *(const float4*)(src + g);
    }
    v[4*k+0] = x.x; v[4*k+1] = x.y; v[4*k+2] = x.z; v[4*k+3] = x.w;
  }

  // ---- reg stages: h=1,2 (j) and h=2048,4096 (k) ----
  #pragma unroll
  for (int k = 0; k < 4; k++) bf4(v[4*k+0], v[4*k+1], v[4*k+2], v[4*k+3]);
  #pragma unroll
  for (int j = 0; j < 4; j++) bf4(v[j], v[4+j], v[8+j], v[12+j]);

  // ---- shuffle stages: h = 4,8,16,32,64,128 (lane bits 0..5) ----
  #pragma unroll
  for (int s = 0; s < 6; s++) {
    const int m = 1 << s;
    const bool hi = (lane & m) != 0;
    #pragma unroll
    for (int i = 0; i < 16; i++) {
      const float p = __shfl_xor(v[i], m, 64);
      v[i] = hi ? (p - v[i]) : (v[i] + p);
    }
  }

  // ---- LDS radix-8 for h=256,512,1024 (wave bits) ----
  #pragma unroll
  for (int k = 0; k < 4; k++) {
    float4 x; x.x=v[4*k+0]; x.y=v[4*k+1]; x.z=v[4*k+2]; x.w=v[4*k+3];
    *(float4*)(lds + swz(2048*k + 4*t)) = x;
  }
  __syncthreads();

  #pragma unroll
  for (int gi = 0; gi < 2; gi++) {
    const int g = t + 512*gi;
    const int glow = g & 255, ghigh = g >> 8;
    const int eb = ghigh*2048 + glow;
    float u[8];
    #pragma unroll
    for (int w = 0; w < 8; w++) u[w] = lds[swz(eb + 256*w)];
    bf4(u[0], u[1], u[2], u[3]);       // h=256,512
    bf4(u[4], u[5], u[6], u[7]);
    #pragma unroll
    for (int i = 0; i < 4; i++) {      // h=1024
      const float a = u[i] + u[i+4], b = u[i] - u[i+4];
      u[i] = a; u[i+4] = b;
    }
    #pragma unroll
    for (int w = 0; w < 8; w++) {      // coalesced: 64 consecutive dwords/wave
      float x = u[w];
      if constexpr (V == 2) x *= NORM11;
      dst[base + eb + 256*w] = x;
    }
  }
}

// ---------------- pass B: FWHT over high 9 bits; 512 rows x 16 cols / block ---------
// Thread map: rg = t&15 (row bits 0-3, lane), cid = (t>>4)&15 (col), t8 = t>>8.
// Per-thread rows r = rg + 16*j + 256*t8, j=0..15.
// Stages: h=16..128 in regs (j bits), h=1..8 via shfl (rg bits),
// h=256 folded into staging transpose (paired butterfly).
#define PBS 20   // LDS row stride (16+4): 2-way banks everywhere, float4-safe

// V=0: Hhi, *2^-11 (in-place) | V=1: Hhi,*2^-11*mask,Hhi (in-place) |
// V=2: Hhi, out = v*2^-11*B + pretrained
template<int V>
__global__ __launch_bounds__(512, 4) void passB(
    const float* __restrict__ src, float* __restrict__ dst,
    const unsigned char* __restrict__ mask,
    const float* __restrict__ bvec, const float* __restrict__ pvec)
{
  __shared__ float lds[512*PBS];   // 40 KB
  const int t = threadIdx.x;
  const int lane = t & 63;
  const long J0 = (long)blockIdx.x * 16;

  // ---- stage in: 2048 float4, 4/thread, 64B-line coalesced ----
  #pragma unroll
  for (int k = 0; k < 4; k++) {
    const int e4 = t + 512*k;
    const int row = e4 >> 2, c4 = (e4 & 3)*4;
    const float4 x = *(const float4*)(src + (long)row*8192 + J0 + c4);
    *(float4*)(lds + row*PBS + c4) = x;
  }
  __syncthreads();

  const int rg = t & 15, cid = (t >> 4) & 15, t8 = t >> 8;

  // ---- transpose read; V1 folds h=256 here ----
  float v[16];
  if constexpr (V == 1) {
    #pragma unroll
    for (int j = 0; j < 16; j++) {
      const int rl = rg + 16*j;
      const float u = lds[rl*PBS + cid];
      const float w = lds[(rl + 256)*PBS + cid];
      v[j] = t8 ? (u - w) : (u + w);
    }
  } else {
    #pragma unroll
    for (int j = 0; j < 16; j++)
      v[j] = lds[(rg + 16*j + 256*t8)*PBS + cid];
  }

  // mask loads issued early (hidden under stage compute)
  unsigned char mreg[16];
  if constexpr (V == 1) {
    #pragma unroll
    for (int j = 0; j < 16; j++)
      mreg[j] = mask[(long)(rg + 16*j + 256*t8)*8192 + J0 + cid];
  }

  // ---- stage set: 4 reg (h=16..128) + 4 shfl (h=1..8) ----
  #pragma unroll
  for (int a = 0; a < 4; a++) bf4(v[4*a+0], v[4*a+1], v[4*a+2], v[4*a+3]);
  #pragma unroll
  for (int b = 0; b < 4; b++) bf4(v[b], v[b+4], v[b+8], v[b+12]);
  #pragma unroll
  for (int s = 0; s < 4; s++) {
    const int m = 1 << s;
    const bool hi = (lane & m) != 0;
    #pragma unroll
    for (int i = 0; i < 16; i++) {
      const float p = __shfl_xor(v[i], m, 64);
      v[i] = hi ? (p - v[i]) : (v[i] + p);
    }
  }

  if constexpr (V == 1) {
    // FWHT2-high complete: *2^-11 * mask, then FWHT3-high (9 more stages)
    #pragma unroll
    for (int j = 0; j < 16; j++) v[j] *= NORM11 * (float)mreg[j];
    #pragma unroll
    for (int a = 0; a < 4; a++) bf4(v[4*a+0], v[4*a+1], v[4*a+2], v[4*a+3]);
    #pragma unroll
    for (int b = 0; b < 4; b++) bf4(v[b], v[b+4], v[b+8], v[b+12]);
    #pragma unroll
    for (int s = 0; s < 4; s++) {
      const int m = 1 << s;
      const bool hi = (lane & m) != 0;
      #pragma unroll
      for (int i = 0; i < 16; i++) {
        const float p = __shfl_xor(v[i], m, 64);
        v[i] = hi ? (p - v[i]) : (v[i] + p);
      }
    }
  }

  // ---- write back (h=256 of the final set still pending) ----
  __syncthreads();
  #pragma unroll
  for (int j = 0; j < 16; j++)
    lds[(rg + 16*j + 256*t8)*PBS + cid] = v[j];
  __syncthreads();

  // ---- out staging with folded h=256: paired butterfly + post-op ----
  #pragma unroll
  for (int k = 0; k < 2; k++) {
    const int e4 = t + 512*k;            // [0,1024)
    const int row = e4 >> 2, c4 = (e4 & 3)*4;   // row in [0,256)
    const float4 u = *(const float4*)(lds + row*PBS + c4);
    const float4 w = *(const float4*)(lds + (row + 256)*PBS + c4);
    float4 lo, hi;
    lo.x = u.x + w.x; lo.y = u.y + w.y; lo.z = u.z + w.z; lo.w = u.w + w.w;
    hi.x = u.x - w.x; hi.y = u.y - w.y; hi.z = u.z - w.z; hi.w = u.w - w.w;
    const long gl = (long)row*8192 + J0 + c4;
    const long gh = (long)(row + 256)*8192 + J0 + c4;
    if constexpr (V == 0) {
      lo.x*=NORM11; lo.y*=NORM11; lo.z*=NORM11; lo.w*=NORM11;
      hi.x*=NORM11; hi.y*=NORM11; hi.z*=NORM11; hi.w*=NORM11;
    }
    if constexpr (V == 2) {
      const float4 bl = *(const float4*)(bvec + gl);
      const float4 pl = *(const float4*)(pvec + gl);
      const float4 bh = *(const float4*)(bvec + gh);
      const float4 ph = *(const float4*)(pvec + gh);
      lo.x = fmaf(lo.x*NORM11, bl.x, pl.x); lo.y = fmaf(lo.y*NORM11, bl.y, pl.y);
      lo.z = fmaf(lo.z*NORM11, bl.z, pl.z); lo.w = fmaf(lo.w*NORM11, bl.w, pl.w);
      hi.x = fmaf(hi.x*NORM11, bh.x, ph.x); hi.y = fmaf(hi.y*NORM11, bh.y, ph.y);
      hi.z = fmaf(hi.z*NORM11, bh.z, ph.z); hi.w = fmaf(hi.w*NORM11, bh.w, ph.w);
    }
    *(float4*)(dst + gl) = lo;
    *(float4*)(dst + gh) = hi;
  }
}

__global__ void scatter_mask(const int* __restrict__ rowIdx,
                             unsigned char* __restrict__ mask, int m)
{
  const int i = blockIdx.x*blockDim.x + threadIdx.x;
  if (i < m) mask[rowIdx[i]] = 1;   // row_idx entries are distinct
}

extern "C" void kernel_launch(void* const* d_in, const int* in_sizes, int n_in,
                              void* d_out, int out_size, void* d_ws, size_t ws_size,
                              hipStream_t stream)
{
  (void)n_in; (void)out_size;
  const float* tv    = (const float*)d_in[0];  // (T, D)
  const float* w     = (const float*)d_in[1];  // (T,)
  const float* prew  = (const float*)d_in[2];  // (D,)
  const float* Bv    = (const float*)d_in[3];
  // d_in[4] = G == ones, unused
  const int*   Pi    = (const int*)d_in[5];
  const int*   invPi = (const int*)d_in[6];
  const int*   rowIx = (const int*)d_in[7];
  const long D = (long)in_sizes[2];            // 2^22
  const int  m = in_sizes[7];
  float* out = (float*)d_out;

  float* bufA; unsigned char* mask;
  const size_t need = (size_t)D*sizeof(float) + (size_t)D;
  if (ws_size >= need) {
    bufA = (float*)d_ws;
    mask = (unsigned char*)d_ws + (size_t)D*sizeof(float);
  } else {
    bufA = (float*)d_in[0];                    // tv fully consumed by K1
    mask = (unsigned char*)((float*)d_in[0] + D);
  }

  const int gA = (int)(D / 8192);  // 512
  const int gB = 8192 / 16;        // 512

  // K1: combine 8 tasks, *B, FWHT1-low          tv -> bufA
  passA<0><<<gA, 512, 0, stream>>>(tv, bufA, Bv, nullptr, w, D);
  hipMemsetAsync(mask, 0, (size_t)D, stream);
  scatter_mask<<<(m + 511)/512, 512, 0, stream>>>(rowIx, mask, m);
  // K2: FWHT1-high, *2^-11                      bufA in-place
  passB<0><<<gB, 512, 0, stream>>>(bufA, bufA, nullptr, nullptr, nullptr);
  // K3: gather Pi, FWHT2-low                    bufA -> out
  passA<1><<<gA, 512, 0, stream>>>(bufA, out, nullptr, Pi, nullptr, D);
  // K4: FWHT2-high, *2^-11, *mask, FWHT3-high   out in-place
  passB<1><<<gB, 512, 0, stream>>>(out, out, mask, nullptr, nullptr);
  // K5: FWHT3-low, *2^-11                       out in-place
  passA<2><<<gA, 512, 0, stream>>>(out, out, nullptr, nullptr, nullptr, D);
  // K6: gather invPi, FWHT4-low                 out -> bufA
  passA<3><<<gA, 512, 0, stream>>>(out, bufA, nullptr, invPi, nullptr, D);
  // K7: FWHT4-high, *2^-11*B + pretrained       bufA -> out
  passB<2><<<gB, 512, 0, stream>>>(bufA, out, nullptr, Bv, prew);
}

// Round 5
// 444.818 us; speedup vs baseline: 1.5020x; 1.0225x over previous
//
#include <hip/hip_runtime.h>

#define NORM11 0x1p-11f   // 1/sqrt(2^22), exact

typedef float v4f __attribute__((ext_vector_type(4)));
typedef int   v4i __attribute__((ext_vector_type(4)));

__device__ __forceinline__ v4f ntld4(const float* p) {
  return __builtin_nontemporal_load((const v4f*)p);
}
__device__ __forceinline__ v4i ntld4i(const int* p) {
  return __builtin_nontemporal_load((const v4i*)p);
}
__device__ __forceinline__ void ntst4(float* p, v4f v) {
  __builtin_nontemporal_store(v, (v4f*)p);
}

// XOR swizzle for pass-A LDS: bits 5-7 -> bank bits 2-4. Involution, float4-safe.
__device__ __forceinline__ int swz(int f) { return f ^ (((f >> 5) & 7) << 2); }

// radix-4 butterfly = two FWHT stages on (a,b,c,d) spaced h, 2h
__device__ __forceinline__ void bf4(float& a, float& b, float& c, float& d) {
  const float ab = a + b, amb = a - b, cd = c + d, cmd = c - d;
  a = ab + cd; b = amb + cmd; c = ab - cd; d = amb - cmd;
}

// ---------------- pass A: FWHT over low 13 bits (one 8192-float span / block) -------
// h=1,2 (float4 lanes) + h=2048,4096 (k) in regs; h=4..128 shfl_xor;
// h=256,512,1024 one LDS radix-8 round trip; coalesced 256B/wave scalar nt stores.
// V=0: pre = B[g]*sum_t w[t]*tv[t][g]; tail zeroes maskT      (K1)
// V=1: pre = src[Pi[g]]   (cached gather)                     (K3)
// V=2: nt load; post *2^-11                                   (K5)
// V=3: pre = src[invPi[g]] (cached gather)                    (K6)
template<int V>
__global__ __launch_bounds__(512, 4) void passA(
    const float* __restrict__ src, float* __restrict__ dst,
    const float* __restrict__ aux, const int* __restrict__ idx,
    const float* __restrict__ w8, long D, unsigned int* __restrict__ maskT32)
{
  __shared__ float lds[8192];
  const int t = threadIdx.x;
  const int lane = t & 63;
  const long base = (long)blockIdx.x * 8192;

  float wr[8];
  if constexpr (V == 0) {
    #pragma unroll
    for (int i = 0; i < 8; i++) wr[i] = w8[i];
  }

  float v[16];
  #pragma unroll
  for (int k = 0; k < 4; k++) {
    const long g = base + 2048*k + 4*t;
    v4f x;
    if constexpr (V == 0) {
      v4f acc = {0.f, 0.f, 0.f, 0.f};
      #pragma unroll
      for (int tt = 0; tt < 8; tt++) {
        const v4f q = ntld4(src + (long)tt*D + g);
        acc += wr[tt] * q;
      }
      x = acc * ntld4(aux + g);
    } else if constexpr (V == 1 || V == 3) {
      const v4i p4 = ntld4i(idx + g);
      x.x = src[p4.x]; x.y = src[p4.y]; x.z = src[p4.z]; x.w = src[p4.w];
    } else {
      x = ntld4(src + g);
    }
    v[4*k+0] = x.x; v[4*k+1] = x.y; v[4*k+2] = x.z; v[4*k+3] = x.w;
  }

  #pragma unroll
  for (int k = 0; k < 4; k++) bf4(v[4*k+0], v[4*k+1], v[4*k+2], v[4*k+3]);
  #pragma unroll
  for (int j = 0; j < 4; j++) bf4(v[j], v[4+j], v[8+j], v[12+j]);

  #pragma unroll
  for (int s = 0; s < 6; s++) {
    const int m = 1 << s;
    const bool hi = (lane & m) != 0;
    #pragma unroll
    for (int i = 0; i < 16; i++) {
      const float p = __shfl_xor(v[i], m, 64);
      v[i] = hi ? (p - v[i]) : (v[i] + p);
    }
  }

  #pragma unroll
  for (int k = 0; k < 4; k++) {
    v4f x; x.x=v[4*k+0]; x.y=v[4*k+1]; x.z=v[4*k+2]; x.w=v[4*k+3];
    *(v4f*)(lds + swz(2048*k + 4*t)) = x;
  }
  __syncthreads();

  #pragma unroll
  for (int gi = 0; gi < 2; gi++) {
    const int g = t + 512*gi;
    const int eb = (g >> 8)*2048 + (g & 255);
    float u[8];
    #pragma unroll
    for (int w = 0; w < 8; w++) u[w] = lds[swz(eb + 256*w)];
    bf4(u[0], u[1], u[2], u[3]);       // h=256,512
    bf4(u[4], u[5], u[6], u[7]);
    #pragma unroll
    for (int i = 0; i < 4; i++) {      // h=1024
      const float a = u[i] + u[i+4], b = u[i] - u[i+4];
      u[i] = a; u[i+4] = b;
    }
    #pragma unroll
    for (int w = 0; w < 8; w++) {      // coalesced: 64 consecutive dwords/wave
      float x = u[w];
      if constexpr (V == 2) x *= NORM11;
      __builtin_nontemporal_store(x, dst + base + eb + 256*w);
    }
  }

  if constexpr (V == 0) {
    // zero this block's maskT slice: 4 MB / 512 blocks = 2048 uints
    const int mb = blockIdx.x * 2048;
    #pragma unroll
    for (int k = 0; k < 4; k++) maskT32[mb + t + 512*k] = 0u;
  }
}

// ---------------- pass B: FWHT over high 9 bits; 512 rows x 16 cols / block ---------
// rg = t&15 (row bits 0-3), cid = (t>>4)&15 (col), t8 = t>>8 (row bit 8).
// h=16..128 regs (j), h=1..8 shfl (rg), h=256 folded into staging transposes.
#define PBS 20   // LDS row stride: 2-way banks, float4-safe

// V=0: Hhi,*2^-11; tail scatters maskT  | V=1: Hhi,*2^-11*maskT,Hhi |
// V=2: Hhi, out = v*2^-11*B + pretrained
template<int V>
__global__ __launch_bounds__(512, 4) void passB(
    const float* __restrict__ src, float* __restrict__ dst,
    const unsigned char* __restrict__ maskT,
    const float* __restrict__ bvec, const float* __restrict__ pvec,
    const int* __restrict__ rowIx, int m)
{
  __shared__ float lds[512*PBS];   // 40 KB
  const int t = threadIdx.x;
  const int lane = t & 63;
  const long J0 = (long)blockIdx.x * 16;

  #pragma unroll
  for (int k = 0; k < 4; k++) {
    const int e4 = t + 512*k;
    const int row = e4 >> 2, c4 = (e4 & 3)*4;
    const v4f x = ntld4(src + (long)row*8192 + J0 + c4);
    *(v4f*)(lds + row*PBS + c4) = x;
  }
  __syncthreads();

  const int rg = t & 15, cid = (t >> 4) & 15, t8 = t >> 8;

  float v[16];
  if constexpr (V == 1) {
    #pragma unroll
    for (int j = 0; j < 16; j++) {
      const int rl = rg + 16*j;
      const float u = lds[rl*PBS + cid];
      const float w = lds[(rl + 256)*PBS + cid];
      v[j] = t8 ? (u - w) : (u + w);
    }
  } else {
    #pragma unroll
    for (int j = 0; j < 16; j++)
      v[j] = lds[(rg + 16*j + 256*t8)*PBS + cid];
  }

  // maskT loads early (contiguous 512B per column, L1/L2 friendly)
  unsigned char mreg[16];
  if constexpr (V == 1) {
    const int cbase = (int)(J0 + cid)*512 + rg + 256*t8;
    #pragma unroll
    for (int j = 0; j < 16; j++) mreg[j] = maskT[cbase + 16*j];
  }

  #pragma unroll
  for (int a = 0; a < 4; a++) bf4(v[4*a+0], v[4*a+1], v[4*a+2], v[4*a+3]);
  #pragma unroll
  for (int b = 0; b < 4; b++) bf4(v[b], v[b+4], v[b+8], v[b+12]);
  #pragma unroll
  for (int s = 0; s < 4; s++) {
    const int m2 = 1 << s;
    const bool hi = (lane & m2) != 0;
    #pragma unroll
    for (int i = 0; i < 16; i++) {
      const float p = __shfl_xor(v[i], m2, 64);
      v[i] = hi ? (p - v[i]) : (v[i] + p);
    }
  }

  if constexpr (V == 1) {
    #pragma unroll
    for (int j = 0; j < 16; j++) v[j] *= NORM11 * (float)mreg[j];
    #pragma unroll
    for (int a = 0; a < 4; a++) bf4(v[4*a+0], v[4*a+1], v[4*a+2], v[4*a+3]);
    #pragma unroll
    for (int b = 0; b < 4; b++) bf4(v[b], v[b+4], v[b+8], v[b+12]);
    #pragma unroll
    for (int s = 0; s < 4; s++) {
      const int m2 = 1 << s;
      const bool hi = (lane & m2) != 0;
      #pragma unroll
      for (int i = 0; i < 16; i++) {
        const float p = __shfl_xor(v[i], m2, 64);
        v[i] = hi ? (p - v[i]) : (v[i] + p);
      }
    }
  }

  __syncthreads();
  #pragma unroll
  for (int j = 0; j < 16; j++)
    lds[(rg + 16*j + 256*t8)*PBS + cid] = v[j];
  __syncthreads();

  // out staging with folded h=256 + post-op, nt stores
  #pragma unroll
  for (int k = 0; k < 2; k++) {
    const int e4 = t + 512*k;
    const int row = e4 >> 2, c4 = (e4 & 3)*4;
    const v4f u = *(const v4f*)(lds + row*PBS + c4);
    const v4f w = *(const v4f*)(lds + (row + 256)*PBS + c4);
    v4f lo = u + w, hi = u - w;
    const long gl = (long)row*8192 + J0 + c4;
    const long gh = (long)(row + 256)*8192 + J0 + c4;
    if constexpr (V == 0) { lo *= NORM11; hi *= NORM11; }
    if constexpr (V == 2) {
      lo = lo*NORM11*ntld4(bvec + gl) + ntld4(pvec + gl);
      hi = hi*NORM11*ntld4(bvec + gh) + ntld4(pvec + gh);
    }
    ntst4(dst + gl, lo);
    ntst4(dst + gh, hi);
  }

  if constexpr (V == 0) {
    // scatter maskT: g -> maskT[(g & 8191)*512 + (g >> 13)]
    unsigned char* mT = (unsigned char*)(dst - (dst - (float*)nullptr, 0), nullptr); // unused
  }
  if constexpr (V == 0) {
    unsigned char* mTw = const_cast<unsigned char*>(maskT);
    const int chunk = (m + 511) / 512;
    const int lo2 = blockIdx.x * chunk;
    const int hi2 = (lo2 + chunk < m) ? lo2 + chunk : m;
    for (int j = lo2 + (int)t; j < hi2; j += 512) {
      const int g = rowIx[j];
      mTw[(long)(g & 8191)*512 + (g >> 13)] = 1;
    }
  }
}

extern "C" void kernel_launch(void* const* d_in, const int* in_sizes, int n_in,
                              void* d_out, int out_size, void* d_ws, size_t ws_size,
                              hipStream_t stream)
{
  (void)n_in; (void)out_size;
  const float* tv    = (const float*)d_in[0];  // (T, D)
  const float* w     = (const float*)d_in[1];  // (T,)
  const float* prew  = (const float*)d_in[2];  // (D,)
  const float* Bv    = (const float*)d_in[3];
  // d_in[4] = G == ones, unused
  const int*   Pi    = (const int*)d_in[5];
  const int*   invPi = (const int*)d_in[6];
  const int*   rowIx = (const int*)d_in[7];
  const long D = (long)in_sizes[2];            // 2^22
  const int  m = in_sizes[7];
  float* out = (float*)d_out;

  // Buffers: A, C (16 MB each) + maskT (4 MB). ws is large; fallback reuses tv
  // (row 0 in-place for A is safe: each K1 block reads all tv rows of its span
  // before writing A's span; rows 1-2 regions hold C/maskT after K1).
  float* A; float* C; unsigned char* maskT;
  const size_t need = 2*(size_t)D*sizeof(float) + (size_t)D;
  if (ws_size >= need) {
    A = (float*)d_ws;
    C = A + D;
    maskT = (unsigned char*)(C + D);
  } else {
    A = (float*)d_in[0];
    C = (float*)d_in[0] + D;
    maskT = (unsigned char*)((float*)d_in[0] + 2*D);
  }

  const int gA = (int)(D / 8192);  // 512
  const int gB = 8192 / 16;        // 512

  // K1: combine 8 tasks, *B, FWHT1-low; zero maskT        tv -> A
  passA<0><<<gA, 512, 0, stream>>>(tv, A, Bv, nullptr, w, D, (unsigned int*)maskT);
  // K2: FWHT1-high, *2^-11; scatter maskT                 A -> C
  passB<0><<<gB, 512, 0, stream>>>(A, C, maskT, nullptr, nullptr, rowIx, m);
  // K3: gather Pi, FWHT2-low                              C -> A
  passA<1><<<gA, 512, 0, stream>>>(C, A, nullptr, Pi, nullptr, D, nullptr);
  // K4: FWHT2-high, *2^-11, *maskT, FWHT3-high            A -> C
  passB<1><<<gB, 512, 0, stream>>>(A, C, maskT, nullptr, nullptr, nullptr, 0);
  // K5: FWHT3-low, *2^-11                                 C -> A
  passA<2><<<gA, 512, 0, stream>>>(C, A, nullptr, nullptr, nullptr, D, nullptr);
  // K6: gather invPi, FWHT4-low                           A -> C
  passA<3><<<gA, 512, 0, stream>>>(A, C, nullptr, invPi, nullptr, D, nullptr);
  // K7: FWHT4-high, *2^-11*B + pretrained                 C -> out
  passB<2><<<gB, 512, 0, stream>>>(C, out, nullptr, Bv, prew, nullptr, 0);
}